// Round 1
// baseline (2926.332 us; speedup 1.0000x reference)
//
#include <hip/hip_runtime.h>
#include <hip/hip_bf16.h>
#include <stdint.h>

#define S_LEN 256
#define BATCH 64
#define HD 256
#define NT 9
#define NTOK (S_LEN*BATCH)   // 16384

__device__ __forceinline__ float bflo(uint32_t u){ union{uint32_t i; float f;} a; a.i = u<<16; return a.f; }
__device__ __forceinline__ float bfhi(uint32_t u){ union{uint32_t i; float f;} a; a.i = u & 0xffff0000u; return a.f; }
__device__ __forceinline__ float sigf(float x){ return 1.f/(1.f+__expf(-x)); }
__device__ __forceinline__ float tanh_(float x){ return 1.f - 2.f/(__expf(2.f*x)+1.f); }
__device__ __forceinline__ float wredsum(float v){
#pragma unroll
  for (int s = 32; s > 0; s >>= 1) v += __shfl_xor(v, s);
  return v;
}

// ---- prep: wT[k][dir*1024+g] = w_ih_dir[g][k]; bias[dir*1024+g] = b_ih+b_hh ----
__global__ void prep_wT(const float* __restrict__ wf, const float* __restrict__ wb,
                        const float* __restrict__ bif, const float* __restrict__ bhf,
                        const float* __restrict__ bib, const float* __restrict__ bhb,
                        float* __restrict__ wT, float* __restrict__ bias){
  int idx = blockIdx.x*256 + threadIdx.x;       // < 256*2048
  int k = idx >> 11;
  int c = idx & 2047;
  const float* w = (c < 1024) ? wf : wb;
  int g = c & 1023;
  wT[idx] = w[g*256 + k];
  if (idx < 2048) {
    bias[idx] = (idx < 1024) ? (bif[idx] + bhf[idx]) : (bib[idx-1024] + bhb[idx-1024]);
  }
}

// ---- prep: pack w_hh (both dirs) into bf16 pairs: wpk[dir][kk][col] = (bf16(w[col][2kk]), bf16(w[col][2kk+1])) ----
__global__ void prep_wpk(const float* __restrict__ whf, const float* __restrict__ whb,
                         uint32_t* __restrict__ wpk){
  int idx = blockIdx.x*256 + threadIdx.x;       // < 2*128*1024
  int dir = idx >> 17;
  int r = idx & 131071;
  int kk = r >> 10;
  int col = r & 1023;
  const float* w = dir ? whb : whf;
  float lo = w[col*256 + 2*kk];
  float hi = w[col*256 + 2*kk + 1];
  __hip_bfloat16 lb = __float2bfloat16(lo), hb = __float2bfloat16(hi);
  uint16_t l16 = *(uint16_t*)&lb, h16 = *(uint16_t*)&hb;
  wpk[idx] = (uint32_t)l16 | ((uint32_t)h16 << 16);
}

// ---- input projection: xproj[t*64+b][col] = emb[inputs[b][t]] . w_ih[col] + bias ----
// A: gathered emb rows (16384 x 256) fp32; B: wT (256 x 2048) fp32; out bf16 split f/b.
__global__ __launch_bounds__(256) void inproj(const int* __restrict__ inp,
    const float* __restrict__ emb, const float* __restrict__ wT,
    const float* __restrict__ bias, __hip_bfloat16* __restrict__ xf,
    __hip_bfloat16* __restrict__ xb){
  __shared__ float As[64][16];
  __shared__ float Bs[16][64];
  __shared__ int toks[64];
  int bm = blockIdx.x, bn = blockIdx.y;
  int tid = threadIdx.x;
  if (tid < 64) {
    int m = bm*64 + tid;                       // m = t*64 + b
    toks[tid] = inp[(m & 63)*S_LEN + (m >> 6)];
  }
  __syncthreads();
  float acc[4][4] = {};
  int ty = tid >> 4, tx = tid & 15;
  int lam = tid >> 2, lak = (tid & 3) * 4;
  int lbk = tid >> 4, lbn = (tid & 15) * 4;
  int tokm = toks[lam];
  for (int k0 = 0; k0 < 256; k0 += 16) {
    float4 av = *(const float4*)(emb + (size_t)tokm*256 + k0 + lak);
    *(float4*)&As[lam][lak] = av;
    float4 bv = *(const float4*)(wT + (size_t)(k0 + lbk)*2048 + bn*64 + lbn);
    *(float4*)&Bs[lbk][lbn] = bv;
    __syncthreads();
#pragma unroll
    for (int kc = 0; kc < 16; ++kc) {
      float a0 = As[ty*4+0][kc], a1 = As[ty*4+1][kc];
      float a2 = As[ty*4+2][kc], a3 = As[ty*4+3][kc];
      float4 b4 = *(float4*)&Bs[kc][tx*4];
      acc[0][0] += a0*b4.x; acc[0][1] += a0*b4.y; acc[0][2] += a0*b4.z; acc[0][3] += a0*b4.w;
      acc[1][0] += a1*b4.x; acc[1][1] += a1*b4.y; acc[1][2] += a1*b4.z; acc[1][3] += a1*b4.w;
      acc[2][0] += a2*b4.x; acc[2][1] += a2*b4.y; acc[2][2] += a2*b4.z; acc[2][3] += a2*b4.w;
      acc[3][0] += a3*b4.x; acc[3][1] += a3*b4.y; acc[3][2] += a3*b4.z; acc[3][3] += a3*b4.w;
    }
    __syncthreads();
  }
  int colb = bn*64 + tx*4;
  float4 bb = *(const float4*)(bias + colb);
  __hip_bfloat16* dst = (bn < 16) ? xf : xb;
  int cb = (bn < 16) ? colb : colb - 1024;
#pragma unroll
  for (int i = 0; i < 4; ++i) {
    int m = bm*64 + ty*4 + i;
    float v0 = acc[i][0] + bb.x;
    float v1 = acc[i][1] + bb.y;
    float v2 = acc[i][2] + bb.z;
    float v3 = acc[i][3] + bb.w;
    __hip_bfloat16 t0 = __float2bfloat16(v0), t1 = __float2bfloat16(v1);
    __hip_bfloat16 t2 = __float2bfloat16(v2), t3 = __float2bfloat16(v3);
    ushort4 st;
    st.x = *(uint16_t*)&t0; st.y = *(uint16_t*)&t1;
    st.z = *(uint16_t*)&t2; st.w = *(uint16_t*)&t3;
    *(ushort4*)&dst[(size_t)m*1024 + cb] = st;
  }
}

// ---- recurrence: one wg per (dir, batch); thread j owns hidden unit j ----
__global__ __launch_bounds__(256) void lstm(const uint32_t* __restrict__ wpk,
    const __hip_bfloat16* __restrict__ xf, const __hip_bfloat16* __restrict__ xb,
    __hip_bfloat16* __restrict__ hout){
  int dir = blockIdx.x >> 6;
  int b = blockIdx.x & 63;
  int j = threadIdx.x;
  __shared__ float hbuf[2][HD];
  hbuf[0][j] = 0.f;
  float c = 0.f;
  const uint32_t* wp = wpk + (size_t)dir*131072 + j;
  const __hip_bfloat16* xp = dir ? xb : xf;
  __syncthreads();
  int cur = 0;
  for (int t = 0; t < S_LEN; ++t) {
    int ts = dir ? (S_LEN-1-t) : t;
    const __hip_bfloat16* x = xp + (size_t)(ts*BATCH + b)*1024;
    float ai = __bfloat162float(x[j]);
    float af = __bfloat162float(x[256+j]);
    float ag = __bfloat162float(x[512+j]);
    float ao = __bfloat162float(x[768+j]);
    const float* h = hbuf[cur];
#pragma unroll 4
    for (int kk = 0; kk < 128; ++kk) {
      float h0 = h[2*kk], h1 = h[2*kk+1];
      uint32_t wi = wp[kk*1024];
      uint32_t wf = wp[kk*1024 + 256];
      uint32_t wg = wp[kk*1024 + 512];
      uint32_t wo = wp[kk*1024 + 768];
      ai += h0*bflo(wi) + h1*bfhi(wi);
      af += h0*bflo(wf) + h1*bfhi(wf);
      ag += h0*bflo(wg) + h1*bfhi(wg);
      ao += h0*bflo(wo) + h1*bfhi(wo);
    }
    float ig = sigf(ai), fg = sigf(af), gg = tanh_(ag), og = sigf(ao);
    c = fg*c + ig*gg;
    float hj = og * tanh_(c);
    hbuf[cur^1][j] = hj;
    hout[(size_t)(ts*BATCH + b)*512 + dir*256 + j] = __float2bfloat16(hj);
    cur ^= 1;
    __syncthreads();
  }
}

// ---- output projection: emissions[t*64+b][j] = h . w_out[j+1] + b_out[j+1] ----
__global__ __launch_bounds__(256) void outproj(const __hip_bfloat16* __restrict__ hb,
    const float* __restrict__ w_out, const float* __restrict__ b_out,
    float* __restrict__ em){
  __shared__ float wsm[NT*512];
  __shared__ float bsm[NT];
  int tid = threadIdx.x;
  for (int i = tid; i < NT*512; i += 256) wsm[i] = w_out[512 + i];  // rows 1..9
  if (tid < NT) bsm[tid] = b_out[1 + tid];
  __syncthreads();
  int wave = tid >> 6, l = tid & 63;
  int m = blockIdx.x*4 + wave;
  const __hip_bfloat16* hp = hb + (size_t)m*512;
  float hv[8];
#pragma unroll
  for (int q = 0; q < 8; ++q) hv[q] = __bfloat162float(hp[l + 64*q]);
  for (int jj = 0; jj < NT; ++jj) {
    float p = 0.f;
#pragma unroll
    for (int q = 0; q < 8; ++q) p += hv[q]*wsm[jj*512 + 64*q + l];
    p = wredsum(p);
    if (l == 0) em[(size_t)m*NT + jj] = p + bsm[jj];
  }
}

// ---- CRF: one wave per batch item; lanes 0..8 hold the 9-state score ----
__global__ __launch_bounds__(64) void crf(const int* __restrict__ tags,
    const float* __restrict__ em, const float* __restrict__ start_t,
    const float* __restrict__ end_t, const float* __restrict__ trans,
    float* __restrict__ part){
  int b = blockIdx.x;
  int l = threadIdx.x;
  // numerator (mask == all ones -> pure sum over t)
  float np = 0.f;
  for (int t = l; t < S_LEN; t += 64) {
    int tg = tags[b*S_LEN + t] - 1;
    float e = em[(size_t)(t*BATCH + b)*NT + tg];
    float tr = (t == 0) ? start_t[tg] : trans[(tags[b*S_LEN + t - 1] - 1)*NT + tg];
    np += e + tr;
  }
  float num = wredsum(np);
  num += end_t[tags[b*S_LEN + S_LEN-1] - 1];
  // denominator: forward algorithm, lane j holds score_j
  int j = (l < NT) ? l : 0;
  float tj[NT];
#pragma unroll
  for (int i = 0; i < NT; ++i) tj[i] = trans[i*NT + j];
  float sc = start_t[j] + em[(size_t)b*NT + j];
  for (int t = 1; t < S_LEN; ++t) {
    float e = em[(size_t)(t*BATCH + b)*NT + j];
    float m = -1e30f;
    float vals[NT];
#pragma unroll
    for (int i = 0; i < NT; ++i) { float si = __shfl(sc, i); vals[i] = si + tj[i]; m = fmaxf(m, vals[i]); }
    float ssum = 0.f;
#pragma unroll
    for (int i = 0; i < NT; ++i) ssum += __expf(vals[i] - m);
    sc = e + m + __logf(ssum);
  }
  float vj = (l < NT) ? (sc + end_t[l]) : -1e30f;
  float mx = vj;
#pragma unroll
  for (int s2 = 32; s2 > 0; s2 >>= 1) mx = fmaxf(mx, __shfl_xor(mx, s2));
  float es = __expf(vj - mx);
  es = wredsum(es);
  if (l == 0) part[b] = num - (mx + __logf(es));
}

__global__ void finalize(const float* __restrict__ part, float* __restrict__ out){
  float v = part[threadIdx.x];
  v = wredsum(v);
  if (threadIdx.x == 0) out[0] = -(v / 64.f);
}

extern "C" void kernel_launch(void* const* d_in, const int* in_sizes, int n_in,
                              void* d_out, int out_size, void* d_ws, size_t ws_size,
                              hipStream_t stream) {
  (void)in_sizes; (void)n_in; (void)out_size; (void)ws_size;
  const int*   inputs  = (const int*)d_in[0];
  const int*   tags    = (const int*)d_in[1];
  // d_in[2] = mask (all ones by construction) -- ignored
  const float* emb     = (const float*)d_in[3];
  const float* w_ih_f  = (const float*)d_in[4];
  const float* w_hh_f  = (const float*)d_in[5];
  const float* b_ih_f  = (const float*)d_in[6];
  const float* b_hh_f  = (const float*)d_in[7];
  const float* w_ih_b  = (const float*)d_in[8];
  const float* w_hh_b  = (const float*)d_in[9];
  const float* b_ih_b  = (const float*)d_in[10];
  const float* b_hh_b  = (const float*)d_in[11];
  const float* w_out   = (const float*)d_in[12];
  const float* b_out   = (const float*)d_in[13];
  const float* start_t = (const float*)d_in[14];
  const float* end_t   = (const float*)d_in[15];
  const float* trans   = (const float*)d_in[16];

  char* ws = (char*)d_ws;
  size_t off = 0;
  auto alloc = [&](size_t bytes) -> void* {
    void* p = ws + off;
    off = (off + bytes + 255) & ~(size_t)255;
    return p;
  };
  __hip_bfloat16* xf  = (__hip_bfloat16*)alloc((size_t)NTOK*1024*2);
  __hip_bfloat16* xb  = (__hip_bfloat16*)alloc((size_t)NTOK*1024*2);
  __hip_bfloat16* hbf = (__hip_bfloat16*)alloc((size_t)NTOK*512*2);
  float*    em   = (float*)alloc((size_t)NTOK*NT*4);
  float*    wT   = (float*)alloc((size_t)256*2048*4);
  float*    bias = (float*)alloc((size_t)2048*4);
  uint32_t* wpk  = (uint32_t*)alloc((size_t)2*128*1024*4);
  float*    part = (float*)alloc((size_t)64*4);

  prep_wT<<<2048, 256, 0, stream>>>(w_ih_f, w_ih_b, b_ih_f, b_hh_f, b_ih_b, b_hh_b, wT, bias);
  prep_wpk<<<1024, 256, 0, stream>>>(w_hh_f, w_hh_b, wpk);
  inproj<<<dim3(256, 32), 256, 0, stream>>>(inputs, emb, wT, bias, xf, xb);
  lstm<<<128, 256, 0, stream>>>(wpk, xf, xb, hbf);
  outproj<<<4096, 256, 0, stream>>>(hbf, w_out, b_out, em);
  crf<<<64, 64, 0, stream>>>(tags, em, start_t, end_t, trans, part);
  finalize<<<1, 64, 0, stream>>>(part, (float*)d_out);
}

// Round 2
// 983.115 us; speedup vs baseline: 2.9766x; 2.9766x over previous
//
#include <hip/hip_runtime.h>
#include <hip/hip_bf16.h>
#include <stdint.h>

#define S_LEN 256
#define BATCH 64
#define HD 256
#define NT 9
#define NTOK (S_LEN*BATCH)   // 16384

#define NREG 92              // w_hh pairs held in VGPRs per thread
#define NLDS 36              // w_hh pairs held in LDS (NREG+NLDS == 128)

typedef _Float16 hf2 __attribute__((ext_vector_type(2)));

__device__ __forceinline__ float sigf(float x){ return 1.f/(1.f+__expf(-x)); }
__device__ __forceinline__ float tanh_(float x){ return 1.f - 2.f/(__expf(2.f*x)+1.f); }
__device__ __forceinline__ float wredsum(float v){
#pragma unroll
  for (int s = 32; s > 0; s >>= 1) v += __shfl_xor(v, s);
  return v;
}

__device__ __forceinline__ float dot2p(uint32_t w, uint32_t h, float acc){
#if __has_builtin(__builtin_amdgcn_fdot2)
  return __builtin_amdgcn_fdot2(__builtin_bit_cast(hf2, w), __builtin_bit_cast(hf2, h), acc, false);
#else
  hf2 wv = __builtin_bit_cast(hf2, w), hv = __builtin_bit_cast(hf2, h);
  return acc + (float)wv.x*(float)hv.x + (float)wv.y*(float)hv.y;
#endif
}

// ---- prep: wT[k][dir*1024+g] = w_ih_dir[g][k]; bias[dir*1024+g] = b_ih+b_hh ----
__global__ void prep_wT(const float* __restrict__ wf, const float* __restrict__ wb,
                        const float* __restrict__ bif, const float* __restrict__ bhf,
                        const float* __restrict__ bib, const float* __restrict__ bhb,
                        float* __restrict__ wT, float* __restrict__ bias){
  int idx = blockIdx.x*256 + threadIdx.x;       // < 256*2048
  int k = idx >> 11;
  int c = idx & 2047;
  const float* w = (c < 1024) ? wf : wb;
  int g = c & 1023;
  wT[idx] = w[g*256 + k];
  if (idx < 2048) {
    bias[idx] = (idx < 1024) ? (bif[idx] + bhf[idx]) : (bib[idx-1024] + bhb[idx-1024]);
  }
}

// ---- prep: pack w_hh into f16 pairs: wph[dir][kk][col] = (h16(w[col][2kk]), h16(w[col][2kk+1])) ----
__global__ void prep_wph(const float* __restrict__ whf, const float* __restrict__ whb,
                         uint32_t* __restrict__ wph){
  int idx = blockIdx.x*256 + threadIdx.x;       // < 2*128*1024
  int dir = idx >> 17;
  int r = idx & 131071;
  int kk = r >> 10;
  int col = r & 1023;
  const float* w = dir ? whb : whf;
  _Float16 lo = (_Float16)w[col*256 + 2*kk];
  _Float16 hi = (_Float16)w[col*256 + 2*kk + 1];
  uint16_t l16 = __builtin_bit_cast(uint16_t, lo);
  uint16_t h16 = __builtin_bit_cast(uint16_t, hi);
  wph[idx] = (uint32_t)l16 | ((uint32_t)h16 << 16);
}

// ---- input projection: xproj[t*64+b][col] = emb[inputs[b][t]] . w_ih[col] + bias ----
__global__ __launch_bounds__(256) void inproj(const int* __restrict__ inp,
    const float* __restrict__ emb, const float* __restrict__ wT,
    const float* __restrict__ bias, __hip_bfloat16* __restrict__ xf,
    __hip_bfloat16* __restrict__ xb){
  __shared__ float As[64][16];
  __shared__ float Bs[16][64];
  __shared__ int toks[64];
  int bm = blockIdx.x, bn = blockIdx.y;
  int tid = threadIdx.x;
  if (tid < 64) {
    int m = bm*64 + tid;                       // m = t*64 + b
    toks[tid] = inp[(m & 63)*S_LEN + (m >> 6)];
  }
  __syncthreads();
  float acc[4][4] = {};
  int ty = tid >> 4, tx = tid & 15;
  int lam = tid >> 2, lak = (tid & 3) * 4;
  int lbk = tid >> 4, lbn = (tid & 15) * 4;
  int tokm = toks[lam];
  for (int k0 = 0; k0 < 256; k0 += 16) {
    float4 av = *(const float4*)(emb + (size_t)tokm*256 + k0 + lak);
    *(float4*)&As[lam][lak] = av;
    float4 bv = *(const float4*)(wT + (size_t)(k0 + lbk)*2048 + bn*64 + lbn);
    *(float4*)&Bs[lbk][lbn] = bv;
    __syncthreads();
#pragma unroll
    for (int kc = 0; kc < 16; ++kc) {
      float a0 = As[ty*4+0][kc], a1 = As[ty*4+1][kc];
      float a2 = As[ty*4+2][kc], a3 = As[ty*4+3][kc];
      float4 b4 = *(float4*)&Bs[kc][tx*4];
      acc[0][0] += a0*b4.x; acc[0][1] += a0*b4.y; acc[0][2] += a0*b4.z; acc[0][3] += a0*b4.w;
      acc[1][0] += a1*b4.x; acc[1][1] += a1*b4.y; acc[1][2] += a1*b4.z; acc[1][3] += a1*b4.w;
      acc[2][0] += a2*b4.x; acc[2][1] += a2*b4.y; acc[2][2] += a2*b4.z; acc[2][3] += a2*b4.w;
      acc[3][0] += a3*b4.x; acc[3][1] += a3*b4.y; acc[3][2] += a3*b4.z; acc[3][3] += a3*b4.w;
    }
    __syncthreads();
  }
  int colb = bn*64 + tx*4;
  float4 bb = *(const float4*)(bias + colb);
  __hip_bfloat16* dst = (bn < 16) ? xf : xb;
  int cb = (bn < 16) ? colb : colb - 1024;
#pragma unroll
  for (int i = 0; i < 4; ++i) {
    int m = bm*64 + ty*4 + i;
    float v0 = acc[i][0] + bb.x;
    float v1 = acc[i][1] + bb.y;
    float v2 = acc[i][2] + bb.z;
    float v3 = acc[i][3] + bb.w;
    __hip_bfloat16 t0 = __float2bfloat16(v0), t1 = __float2bfloat16(v1);
    __hip_bfloat16 t2 = __float2bfloat16(v2), t3 = __float2bfloat16(v3);
    ushort4 st;
    st.x = *(uint16_t*)&t0; st.y = *(uint16_t*)&t1;
    st.z = *(uint16_t*)&t2; st.w = *(uint16_t*)&t3;
    *(ushort4*)&dst[(size_t)m*1024 + cb] = st;
  }
}

// ---- recurrence: one wg per (dir, batch); 1024 threads; thread gc owns gate column gc ----
// Weight-stationary: 92 f16-pairs in VGPRs + 36 pairs in LDS per column.
__global__ __launch_bounds__(1024, 1) void lstm2(const uint32_t* __restrict__ wph,
    const __hip_bfloat16* __restrict__ xf, const __hip_bfloat16* __restrict__ xb,
    __hip_bfloat16* __restrict__ hout){
  int dir = blockIdx.x >> 6;
  int b = blockIdx.x & 63;
  int gc = threadIdx.x;                 // gate column 0..1023 (gate = gc>>8, unit = gc&255)
  __shared__ uint32_t wl[NLDS][1024];   // 144 KB
  __shared__ float zs[1024];            // 4 KB
  __shared__ _Float16 hs[256];          // 512 B

  const uint32_t* wp = wph + (size_t)dir*131072 + gc;
  uint32_t wreg[NREG];
#pragma unroll
  for (int r = 0; r < NREG; ++r) wreg[r] = wp[r*1024];
  for (int r = 0; r < NLDS; ++r) wl[r][gc] = wp[(NREG + r)*1024];
  if (gc < 256) hs[gc] = (_Float16)0.f;
  float c = 0.f;
  const __hip_bfloat16* xp = (dir ? xb : xf) + (size_t)b*1024 + gc;
  __syncthreads();

  for (int t = 0; t < S_LEN; ++t) {
    int ts = dir ? (S_LEN-1-t) : t;
    float xv = __bfloat162float(xp[(size_t)ts*65536]);
    float acc0 = 0.f, acc1 = 0.f;
    const uint4* hp4 = (const uint4*)hs;   // 32 uint4 = 128 h-pairs (uniform broadcast)
#pragma unroll
    for (int q = 0; q < 23; ++q) {         // pairs 0..91 from registers
      uint4 hq = hp4[q];
      acc0 = dot2p(wreg[4*q+0], hq.x, acc0);
      acc1 = dot2p(wreg[4*q+1], hq.y, acc1);
      acc0 = dot2p(wreg[4*q+2], hq.z, acc0);
      acc1 = dot2p(wreg[4*q+3], hq.w, acc1);
    }
#pragma unroll
    for (int q = 23; q < 32; ++q) {        // pairs 92..127 from LDS
      uint4 hq = hp4[q];
      int r = 4*q - NREG;
      acc0 = dot2p(wl[r+0][gc], hq.x, acc0);
      acc1 = dot2p(wl[r+1][gc], hq.y, acc1);
      acc0 = dot2p(wl[r+2][gc], hq.z, acc0);
      acc1 = dot2p(wl[r+3][gc], hq.w, acc1);
    }
    zs[gc] = xv + acc0 + acc1;
    __syncthreads();
    if (gc < 256) {
      float zi = zs[gc], zf = zs[gc+256], zg = zs[gc+512], zo = zs[gc+768];
      float ig = sigf(zi), fg = sigf(zf), gg = tanh_(zg), og = sigf(zo);
      c = fg*c + ig*gg;
      float hj = og * tanh_(c);
      hs[gc] = (_Float16)hj;
      hout[((size_t)ts*BATCH + b)*512 + dir*256 + gc] = __float2bfloat16(hj);
    }
    __syncthreads();
  }
}

// ---- output projection: emissions[t*64+b][j] = h . w_out[j+1] + b_out[j+1] ----
__global__ __launch_bounds__(256) void outproj(const __hip_bfloat16* __restrict__ hb,
    const float* __restrict__ w_out, const float* __restrict__ b_out,
    float* __restrict__ em){
  __shared__ float wsm[NT*512];
  __shared__ float bsm[NT];
  int tid = threadIdx.x;
  for (int i = tid; i < NT*512; i += 256) wsm[i] = w_out[512 + i];  // rows 1..9
  if (tid < NT) bsm[tid] = b_out[1 + tid];
  __syncthreads();
  int wave = tid >> 6, l = tid & 63;
  int m = blockIdx.x*4 + wave;
  const __hip_bfloat16* hp = hb + (size_t)m*512;
  float hv[8];
#pragma unroll
  for (int q = 0; q < 8; ++q) hv[q] = __bfloat162float(hp[l + 64*q]);
  for (int jj = 0; jj < NT; ++jj) {
    float p = 0.f;
#pragma unroll
    for (int q = 0; q < 8; ++q) p += hv[q]*wsm[jj*512 + 64*q + l];
    p = wredsum(p);
    if (l == 0) em[(size_t)m*NT + jj] = p + bsm[jj];
  }
}

// ---- CRF: one wave per batch item; lanes 0..8 hold the 9-state score ----
__global__ __launch_bounds__(64) void crf(const int* __restrict__ tags,
    const float* __restrict__ em, const float* __restrict__ start_t,
    const float* __restrict__ end_t, const float* __restrict__ trans,
    float* __restrict__ part){
  int b = blockIdx.x;
  int l = threadIdx.x;
  float np = 0.f;
  for (int t = l; t < S_LEN; t += 64) {
    int tg = tags[b*S_LEN + t] - 1;
    float e = em[(size_t)(t*BATCH + b)*NT + tg];
    float tr = (t == 0) ? start_t[tg] : trans[(tags[b*S_LEN + t - 1] - 1)*NT + tg];
    np += e + tr;
  }
  float num = wredsum(np);
  num += end_t[tags[b*S_LEN + S_LEN-1] - 1];
  int j = (l < NT) ? l : 0;
  float tj[NT];
#pragma unroll
  for (int i = 0; i < NT; ++i) tj[i] = trans[i*NT + j];
  float sc = start_t[j] + em[(size_t)b*NT + j];
  for (int t = 1; t < S_LEN; ++t) {
    float e = em[(size_t)(t*BATCH + b)*NT + j];
    float m = -1e30f;
    float vals[NT];
#pragma unroll
    for (int i = 0; i < NT; ++i) { float si = __shfl(sc, i); vals[i] = si + tj[i]; m = fmaxf(m, vals[i]); }
    float ssum = 0.f;
#pragma unroll
    for (int i = 0; i < NT; ++i) ssum += __expf(vals[i] - m);
    sc = e + m + __logf(ssum);
  }
  float vj = (l < NT) ? (sc + end_t[l]) : -1e30f;
  float mx = vj;
#pragma unroll
  for (int s2 = 32; s2 > 0; s2 >>= 1) mx = fmaxf(mx, __shfl_xor(mx, s2));
  float es = __expf(vj - mx);
  es = wredsum(es);
  if (l == 0) part[b] = num - (mx + __logf(es));
}

__global__ void finalize(const float* __restrict__ part, float* __restrict__ out){
  float v = part[threadIdx.x];
  v = wredsum(v);
  if (threadIdx.x == 0) out[0] = -(v / 64.f);
}

extern "C" void kernel_launch(void* const* d_in, const int* in_sizes, int n_in,
                              void* d_out, int out_size, void* d_ws, size_t ws_size,
                              hipStream_t stream) {
  (void)in_sizes; (void)n_in; (void)out_size; (void)ws_size;
  const int*   inputs  = (const int*)d_in[0];
  const int*   tags    = (const int*)d_in[1];
  const float* emb     = (const float*)d_in[3];
  const float* w_ih_f  = (const float*)d_in[4];
  const float* w_hh_f  = (const float*)d_in[5];
  const float* b_ih_f  = (const float*)d_in[6];
  const float* b_hh_f  = (const float*)d_in[7];
  const float* w_ih_b  = (const float*)d_in[8];
  const float* w_hh_b  = (const float*)d_in[9];
  const float* b_ih_b  = (const float*)d_in[10];
  const float* b_hh_b  = (const float*)d_in[11];
  const float* w_out   = (const float*)d_in[12];
  const float* b_out   = (const float*)d_in[13];
  const float* start_t = (const float*)d_in[14];
  const float* end_t   = (const float*)d_in[15];
  const float* trans   = (const float*)d_in[16];

  char* ws = (char*)d_ws;
  size_t off = 0;
  auto alloc = [&](size_t bytes) -> void* {
    void* p = ws + off;
    off = (off + bytes + 255) & ~(size_t)255;
    return p;
  };
  __hip_bfloat16* xf  = (__hip_bfloat16*)alloc((size_t)NTOK*1024*2);
  __hip_bfloat16* xb  = (__hip_bfloat16*)alloc((size_t)NTOK*1024*2);
  __hip_bfloat16* hbf = (__hip_bfloat16*)alloc((size_t)NTOK*512*2);
  float*    em   = (float*)alloc((size_t)NTOK*NT*4);
  float*    wT   = (float*)alloc((size_t)256*2048*4);
  float*    bias = (float*)alloc((size_t)2048*4);
  uint32_t* wph  = (uint32_t*)alloc((size_t)2*128*1024*4);
  float*    part = (float*)alloc((size_t)64*4);

  prep_wT<<<2048, 256, 0, stream>>>(w_ih_f, w_ih_b, b_ih_f, b_hh_f, b_ih_b, b_hh_b, wT, bias);
  prep_wph<<<1024, 256, 0, stream>>>(w_hh_f, w_hh_b, wph);
  inproj<<<dim3(256, 32), 256, 0, stream>>>(inputs, emb, wT, bias, xf, xb);
  lstm2<<<128, 1024, 0, stream>>>(wph, xf, xb, hbf);
  outproj<<<4096, 256, 0, stream>>>(hbf, w_out, b_out, em);
  crf<<<64, 64, 0, stream>>>(tags, em, start_t, end_t, trans, part);
  finalize<<<1, 64, 0, stream>>>(part, (float*)d_out);
}

// Round 3
// 795.032 us; speedup vs baseline: 3.6808x; 1.2366x over previous
//
#include <hip/hip_runtime.h>
#include <hip/hip_bf16.h>
#include <stdint.h>

#define S_LEN 256
#define BATCH 64
#define HD 256
#define NT 9
#define NTOK (S_LEN*BATCH)   // 16384

#define NREG 92              // w_hh pairs held in VGPRs per thread
#define NLDS 36              // w_hh pairs held in LDS (NREG+NLDS == 128)

typedef _Float16 hf2 __attribute__((ext_vector_type(2)));
typedef short bf16x8 __attribute__((ext_vector_type(8)));
typedef float f32x4 __attribute__((ext_vector_type(4)));

__device__ __forceinline__ float sigf(float x){ return 1.f/(1.f+__expf(-x)); }
__device__ __forceinline__ float tanh_(float x){ return 1.f - 2.f/(__expf(2.f*x)+1.f); }
__device__ __forceinline__ float wredsum(float v){
#pragma unroll
  for (int s = 32; s > 0; s >>= 1) v += __shfl_xor(v, s);
  return v;
}
__device__ __forceinline__ uint16_t f2b(float f){
  __hip_bfloat16 h = __float2bfloat16(f);
  return *(uint16_t*)&h;
}

__device__ __forceinline__ float dot2p(uint32_t w, uint32_t h, float acc){
#if __has_builtin(__builtin_amdgcn_fdot2)
  return __builtin_amdgcn_fdot2(__builtin_bit_cast(hf2, w), __builtin_bit_cast(hf2, h), acc, false);
#else
  hf2 wv = __builtin_bit_cast(hf2, w), hv = __builtin_bit_cast(hf2, h);
  return acc + (float)wv.x*(float)hv.x + (float)wv.y*(float)hv.y;
#endif
}

// ---- prep: wih16[n][k] = bf16(w_ih_dir[g][k]) (n = dir*1024+g); bias[n] = b_ih+b_hh ----
__global__ void prep2(const float* __restrict__ wihf, const float* __restrict__ wihb,
                      const float* __restrict__ bif, const float* __restrict__ bhf,
                      const float* __restrict__ bib, const float* __restrict__ bhb,
                      uint16_t* __restrict__ wih16, float* __restrict__ bias){
  int idx = blockIdx.x*256 + threadIdx.x;       // < 2048*256
  int n = idx >> 8;
  int k = idx & 255;
  const float* w = (n < 1024) ? wihf : wihb;
  int g = n & 1023;
  wih16[idx] = f2b(w[g*256 + k]);
  if (idx < 2048) {
    bias[idx] = (idx < 1024) ? (bif[idx] + bhf[idx]) : (bib[idx-1024] + bhb[idx-1024]);
  }
}

// ---- prep: pack w_hh into f16 pairs: wph[dir][kk][col] = (h16(w[col][2kk]), h16(w[col][2kk+1])) ----
__global__ void prep_wph(const float* __restrict__ whf, const float* __restrict__ whb,
                         uint32_t* __restrict__ wph){
  int idx = blockIdx.x*256 + threadIdx.x;       // < 2*128*1024
  int dir = idx >> 17;
  int r = idx & 131071;
  int kk = r >> 10;
  int col = r & 1023;
  const float* w = dir ? whb : whf;
  _Float16 lo = (_Float16)w[col*256 + 2*kk];
  _Float16 hi = (_Float16)w[col*256 + 2*kk + 1];
  uint16_t l16 = __builtin_bit_cast(uint16_t, lo);
  uint16_t h16 = __builtin_bit_cast(uint16_t, hi);
  wph[idx] = (uint32_t)l16 | ((uint32_t)h16 << 16);
}

// ---- input projection via MFMA: x[m][n] = emb[tok(m)] . w_ih[n] + bias[n] ----
// m = t*64+b (M=16384), n global col (N=2048, both dirs). Block tile 64x128, K-chunk 64.
__global__ __launch_bounds__(256) void inproj_mfma(const int* __restrict__ inp,
    const float* __restrict__ emb, const uint16_t* __restrict__ wih16,
    const float* __restrict__ bias, __hip_bfloat16* __restrict__ xf,
    __hip_bfloat16* __restrict__ xb){
  __shared__ uint16_t As[64][72];    // A[m][k] bf16, +8 pad
  __shared__ uint16_t Bs[128][72];   // B^T[c][k] = w_ih[n0+c][k] bf16, +8 pad
  __shared__ int toks[64];
  int bm = blockIdx.x, bn = blockIdx.y;
  int tid = threadIdx.x;
  if (tid < 64) {
    int m = bm*64 + tid;                       // b = m&63, t = m>>6
    toks[tid] = inp[(m & 63)*S_LEN + (m >> 6)];
  }
  __syncthreads();
  int w = tid >> 6, l = tid & 63;
  int lr = l & 15, lg = l >> 4;
  f32x4 acc[8];
#pragma unroll
  for (int cf = 0; cf < 8; ++cf) acc[cf] = (f32x4){0.f,0.f,0.f,0.f};

  int am = tid >> 2, aq = tid & 3;             // A staging: row am, 16 k each
  int bc = tid >> 1, bh = tid & 1;             // B staging: row bc, 32 k each

  for (int k0 = 0; k0 < 256; k0 += 64) {
    // stage A (convert f32 -> bf16)
    {
      const float* asrc = emb + (size_t)toks[am]*256 + k0 + aq*16;
      float4 v0 = *(const float4*)(asrc+0);
      float4 v1 = *(const float4*)(asrc+4);
      float4 v2 = *(const float4*)(asrc+8);
      float4 v3 = *(const float4*)(asrc+12);
      uint16_t t16[16];
      t16[0]=f2b(v0.x); t16[1]=f2b(v0.y); t16[2]=f2b(v0.z); t16[3]=f2b(v0.w);
      t16[4]=f2b(v1.x); t16[5]=f2b(v1.y); t16[6]=f2b(v1.z); t16[7]=f2b(v1.w);
      t16[8]=f2b(v2.x); t16[9]=f2b(v2.y); t16[10]=f2b(v2.z); t16[11]=f2b(v2.w);
      t16[12]=f2b(v3.x); t16[13]=f2b(v3.y); t16[14]=f2b(v3.z); t16[15]=f2b(v3.w);
      *(uint4*)&As[am][aq*16]     = *(uint4*)&t16[0];
      *(uint4*)&As[am][aq*16 + 8] = *(uint4*)&t16[8];
    }
    // stage B (already bf16)
    {
      const uint16_t* bsrc = wih16 + (size_t)(bn*128 + bc)*256 + k0 + bh*32;
      uint4 b0 = *(const uint4*)(bsrc+0);
      uint4 b1 = *(const uint4*)(bsrc+8);
      uint4 b2 = *(const uint4*)(bsrc+16);
      uint4 b3 = *(const uint4*)(bsrc+24);
      *(uint4*)&Bs[bc][bh*32+0]  = b0;
      *(uint4*)&Bs[bc][bh*32+8]  = b1;
      *(uint4*)&Bs[bc][bh*32+16] = b2;
      *(uint4*)&Bs[bc][bh*32+24] = b3;
    }
    __syncthreads();
#pragma unroll
    for (int ks = 0; ks < 2; ++ks) {
      int koff = ks*32 + lg*8;
      bf16x8 a = *(const bf16x8*)&As[16*w + lr][koff];
#pragma unroll
      for (int cf = 0; cf < 8; ++cf) {
        bf16x8 b = *(const bf16x8*)&Bs[cf*16 + lr][koff];
        acc[cf] = __builtin_amdgcn_mfma_f32_16x16x32_bf16(a, b, acc[cf], 0, 0, 0);
      }
    }
    __syncthreads();
  }
  // epilogue: D row = lg*4 + r, col = lr  (m89-verified C/D layout)
  int n0 = bn*128;
  bool back = (n0 >= 1024);
  __hip_bfloat16* dst = back ? xb : xf;
  int nb0 = back ? (n0 - 1024) : n0;
#pragma unroll
  for (int cf = 0; cf < 8; ++cf) {
    int nc = cf*16 + lr;
    float bv = bias[n0 + nc];
#pragma unroll
    for (int r = 0; r < 4; ++r) {
      int m = bm*64 + 16*w + lg*4 + r;
      dst[(size_t)m*1024 + nb0 + nc] = __float2bfloat16(acc[cf][r] + bv);
    }
  }
}

// ---- recurrence: one wg per (dir, batch); 1024 threads; thread gc owns gate column gc ----
// Weight-stationary: 92 f16-pairs pinned in VGPRs + 36 pairs in LDS per column.
__global__ __launch_bounds__(1024)
__attribute__((amdgpu_waves_per_eu(4, 4)))
void lstm2(const uint32_t* __restrict__ wph,
    const __hip_bfloat16* __restrict__ xf, const __hip_bfloat16* __restrict__ xb,
    __hip_bfloat16* __restrict__ hout){
  int dir = blockIdx.x >> 6;
  int b = blockIdx.x & 63;
  int gc = threadIdx.x;                 // gate column 0..1023 (gate = gc>>8, unit = gc&255)
  __shared__ uint32_t wl[NLDS][1024];   // 144 KB
  __shared__ float zs[1024];            // 4 KB
  __shared__ __align__(16) _Float16 hs[256];

  const uint32_t* wp = wph + (size_t)dir*131072 + gc;
  uint32_t wreg[NREG];
#pragma unroll
  for (int r = 0; r < NREG; ++r) wreg[r] = wp[r*1024];
  for (int r = 0; r < NLDS; ++r) wl[r][gc] = wp[(NREG + r)*1024];
  // Pin weights in VGPRs: forbid remat/sink of the loads into the loop.
#pragma unroll
  for (int r = 0; r < NREG; ++r) asm volatile("" : "+v"(wreg[r]));
  asm volatile("" ::: "memory");
  if (gc < 256) hs[gc] = (_Float16)0.f;
  float c = 0.f;
  const __hip_bfloat16* xp = (dir ? xb : xf) + (size_t)b*1024 + gc;
  __syncthreads();

  int ts0 = dir ? (S_LEN-1) : 0;
  float xv = __bfloat162float(xp[(size_t)ts0*65536]);
  for (int t = 0; t < S_LEN; ++t) {
    int ts = dir ? (S_LEN-1-t) : t;
    // prefetch next step's x (hidden under the dot loop)
    float xnext = xv;
    if (t + 1 < S_LEN) {
      int tn = dir ? (S_LEN-2-t) : (t+1);
      xnext = __bfloat162float(xp[(size_t)tn*65536]);
    }
    float acc0 = 0.f, acc1 = 0.f;
    const uint4* hp4 = (const uint4*)hs;   // 32 uint4 = 128 h-pairs (uniform broadcast)
#pragma unroll
    for (int q = 0; q < 23; ++q) {         // pairs 0..91 from registers
      uint4 hq = hp4[q];
      acc0 = dot2p(wreg[4*q+0], hq.x, acc0);
      acc1 = dot2p(wreg[4*q+1], hq.y, acc1);
      acc0 = dot2p(wreg[4*q+2], hq.z, acc0);
      acc1 = dot2p(wreg[4*q+3], hq.w, acc1);
    }
#pragma unroll
    for (int q = 23; q < 32; ++q) {        // pairs 92..127 from LDS
      uint4 hq = hp4[q];
      int r = 4*q - NREG;
      acc0 = dot2p(wl[r+0][gc], hq.x, acc0);
      acc1 = dot2p(wl[r+1][gc], hq.y, acc1);
      acc0 = dot2p(wl[r+2][gc], hq.z, acc0);
      acc1 = dot2p(wl[r+3][gc], hq.w, acc1);
    }
    zs[gc] = xv + acc0 + acc1;
    __syncthreads();
    if (gc < 256) {
      float zi = zs[gc], zf = zs[gc+256], zg = zs[gc+512], zo = zs[gc+768];
      float ig = sigf(zi), fg = sigf(zf), gg = tanh_(zg), og = sigf(zo);
      c = fg*c + ig*gg;
      float hj = og * tanh_(c);
      hs[gc] = (_Float16)hj;
      hout[((size_t)ts*BATCH + b)*512 + dir*256 + gc] = __float2bfloat16(hj);
    }
    xv = xnext;
    __syncthreads();
  }
}

// ---- output projection: emissions[t*64+b][j] = h . w_out[j+1] + b_out[j+1] ----
__global__ __launch_bounds__(256) void outproj(const __hip_bfloat16* __restrict__ hb,
    const float* __restrict__ w_out, const float* __restrict__ b_out,
    float* __restrict__ em){
  __shared__ float wsm[NT*512];
  __shared__ float bsm[NT];
  int tid = threadIdx.x;
  for (int i = tid; i < NT*512; i += 256) wsm[i] = w_out[512 + i];  // rows 1..9
  if (tid < NT) bsm[tid] = b_out[1 + tid];
  __syncthreads();
  int wave = tid >> 6, l = tid & 63;
  int m = blockIdx.x*4 + wave;
  const __hip_bfloat16* hp = hb + (size_t)m*512;
  float hv[8];
#pragma unroll
  for (int q = 0; q < 8; ++q) hv[q] = __bfloat162float(hp[l + 64*q]);
  for (int jj = 0; jj < NT; ++jj) {
    float p = 0.f;
#pragma unroll
    for (int q = 0; q < 8; ++q) p += hv[q]*wsm[jj*512 + 64*q + l];
    p = wredsum(p);
    if (l == 0) em[(size_t)m*NT + jj] = p + bsm[jj];
  }
}

// ---- CRF: one wave per batch item; lanes 0..8 hold the 9-state score ----
__global__ __launch_bounds__(64) void crf(const int* __restrict__ tags,
    const float* __restrict__ em, const float* __restrict__ start_t,
    const float* __restrict__ end_t, const float* __restrict__ trans,
    float* __restrict__ part){
  int b = blockIdx.x;
  int l = threadIdx.x;
  float np = 0.f;
  for (int t = l; t < S_LEN; t += 64) {
    int tg = tags[b*S_LEN + t] - 1;
    float e = em[(size_t)(t*BATCH + b)*NT + tg];
    float tr = (t == 0) ? start_t[tg] : trans[(tags[b*S_LEN + t - 1] - 1)*NT + tg];
    np += e + tr;
  }
  float num = wredsum(np);
  num += end_t[tags[b*S_LEN + S_LEN-1] - 1];
  int j = (l < NT) ? l : 0;
  float tj[NT];
#pragma unroll
  for (int i = 0; i < NT; ++i) tj[i] = trans[i*NT + j];
  float sc = start_t[j] + em[(size_t)b*NT + j];
  for (int t = 1; t < S_LEN; ++t) {
    float e = em[(size_t)(t*BATCH + b)*NT + j];
    float m = -1e30f;
    float vals[NT];
#pragma unroll
    for (int i = 0; i < NT; ++i) { float si = __shfl(sc, i); vals[i] = si + tj[i]; m = fmaxf(m, vals[i]); }
    float ssum = 0.f;
#pragma unroll
    for (int i = 0; i < NT; ++i) ssum += __expf(vals[i] - m);
    sc = e + m + __logf(ssum);
  }
  float vj = (l < NT) ? (sc + end_t[l]) : -1e30f;
  float mx = vj;
#pragma unroll
  for (int s2 = 32; s2 > 0; s2 >>= 1) mx = fmaxf(mx, __shfl_xor(mx, s2));
  float es = __expf(vj - mx);
  es = wredsum(es);
  if (l == 0) part[b] = num - (mx + __logf(es));
}

__global__ void finalize(const float* __restrict__ part, float* __restrict__ out){
  float v = part[threadIdx.x];
  v = wredsum(v);
  if (threadIdx.x == 0) out[0] = -(v / 64.f);
}

extern "C" void kernel_launch(void* const* d_in, const int* in_sizes, int n_in,
                              void* d_out, int out_size, void* d_ws, size_t ws_size,
                              hipStream_t stream) {
  (void)in_sizes; (void)n_in; (void)out_size; (void)ws_size;
  const int*   inputs  = (const int*)d_in[0];
  const int*   tags    = (const int*)d_in[1];
  const float* emb     = (const float*)d_in[3];
  const float* w_ih_f  = (const float*)d_in[4];
  const float* w_hh_f  = (const float*)d_in[5];
  const float* b_ih_f  = (const float*)d_in[6];
  const float* b_hh_f  = (const float*)d_in[7];
  const float* w_ih_b  = (const float*)d_in[8];
  const float* w_hh_b  = (const float*)d_in[9];
  const float* b_ih_b  = (const float*)d_in[10];
  const float* b_hh_b  = (const float*)d_in[11];
  const float* w_out   = (const float*)d_in[12];
  const float* b_out   = (const float*)d_in[13];
  const float* start_t = (const float*)d_in[14];
  const float* end_t   = (const float*)d_in[15];
  const float* trans   = (const float*)d_in[16];

  char* ws = (char*)d_ws;
  size_t off = 0;
  auto alloc = [&](size_t bytes) -> void* {
    void* p = ws + off;
    off = (off + bytes + 255) & ~(size_t)255;
    return p;
  };
  __hip_bfloat16* xf  = (__hip_bfloat16*)alloc((size_t)NTOK*1024*2);
  __hip_bfloat16* xb  = (__hip_bfloat16*)alloc((size_t)NTOK*1024*2);
  __hip_bfloat16* hbf = (__hip_bfloat16*)alloc((size_t)NTOK*512*2);
  float*    em    = (float*)alloc((size_t)NTOK*NT*4);
  uint16_t* wih16 = (uint16_t*)alloc((size_t)2048*256*2);
  float*    bias  = (float*)alloc((size_t)2048*4);
  uint32_t* wph   = (uint32_t*)alloc((size_t)2*128*1024*4);
  float*    part  = (float*)alloc((size_t)64*4);

  prep2<<<2048, 256, 0, stream>>>(w_ih_f, w_ih_b, b_ih_f, b_hh_f, b_ih_b, b_hh_b, wih16, bias);
  prep_wph<<<1024, 256, 0, stream>>>(w_hh_f, w_hh_b, wph);
  inproj_mfma<<<dim3(256, 16), 256, 0, stream>>>(inputs, emb, wih16, bias, xf, xb);
  lstm2<<<128, 1024, 0, stream>>>(wph, xf, xb, hbf);
  outproj<<<4096, 256, 0, stream>>>(hbf, w_out, b_out, em);
  crf<<<64, 64, 0, stream>>>(tags, em, start_t, end_t, trans, part);
  finalize<<<1, 64, 0, stream>>>(part, (float*)d_out);
}

// Round 4
// 726.403 us; speedup vs baseline: 4.0285x; 1.0945x over previous
//
#include <hip/hip_runtime.h>
#include <hip/hip_bf16.h>
#include <stdint.h>

#define S_LEN 256
#define BATCH 64
#define HD 256
#define NT 9
#define NTOK (S_LEN*BATCH)   // 16384

#define NREG 96              // w_hh pairs held in VGPRs per thread
#define NLDS2 16             // uint2 rows in LDS (32 pairs; NREG + 2*NLDS2 == 128)

typedef _Float16 hf2 __attribute__((ext_vector_type(2)));
typedef short bf16x8 __attribute__((ext_vector_type(8)));
typedef float f32x4 __attribute__((ext_vector_type(4)));

__device__ __forceinline__ float sigf(float x){ return 1.f/(1.f+__expf(-x)); }
__device__ __forceinline__ float tanh_(float x){ return 1.f - 2.f/(__expf(2.f*x)+1.f); }
__device__ __forceinline__ float wredsum(float v){
#pragma unroll
  for (int s = 32; s > 0; s >>= 1) v += __shfl_xor(v, s);
  return v;
}
__device__ __forceinline__ uint16_t f2b(float f){
  __hip_bfloat16 h = __float2bfloat16(f);
  return *(uint16_t*)&h;
}

__device__ __forceinline__ float dot2p(uint32_t w, uint32_t h, float acc){
#if __has_builtin(__builtin_amdgcn_fdot2)
  return __builtin_amdgcn_fdot2(__builtin_bit_cast(hf2, w), __builtin_bit_cast(hf2, h), acc, false);
#else
  hf2 wv = __builtin_bit_cast(hf2, w), hv = __builtin_bit_cast(hf2, h);
  return acc + (float)wv.x*(float)hv.x + (float)wv.y*(float)hv.y;
#endif
}

// ---- prep: wih16[n][k] = bf16(w_ih_dir[g][k]) (n = dir*1024+g); bias[n] = b_ih+b_hh ----
__global__ void prep2(const float* __restrict__ wihf, const float* __restrict__ wihb,
                      const float* __restrict__ bif, const float* __restrict__ bhf,
                      const float* __restrict__ bib, const float* __restrict__ bhb,
                      uint16_t* __restrict__ wih16, float* __restrict__ bias){
  int idx = blockIdx.x*256 + threadIdx.x;       // < 2048*256
  int n = idx >> 8;
  int k = idx & 255;
  const float* w = (n < 1024) ? wihf : wihb;
  int g = n & 1023;
  wih16[idx] = f2b(w[g*256 + k]);
  if (idx < 2048) {
    bias[idx] = (idx < 1024) ? (bif[idx] + bhf[idx]) : (bib[idx-1024] + bhb[idx-1024]);
  }
}

// ---- prep: pack w_hh into f16 pairs: wph[dir][kk][col] = (h16(w[col][2kk]), h16(w[col][2kk+1])) ----
__global__ void prep_wph(const float* __restrict__ whf, const float* __restrict__ whb,
                         uint32_t* __restrict__ wph){
  int idx = blockIdx.x*256 + threadIdx.x;       // < 2*128*1024
  int dir = idx >> 17;
  int r = idx & 131071;
  int kk = r >> 10;
  int col = r & 1023;
  const float* w = dir ? whb : whf;
  _Float16 lo = (_Float16)w[col*256 + 2*kk];
  _Float16 hi = (_Float16)w[col*256 + 2*kk + 1];
  uint16_t l16 = __builtin_bit_cast(uint16_t, lo);
  uint16_t h16 = __builtin_bit_cast(uint16_t, hi);
  wph[idx] = (uint32_t)l16 | ((uint32_t)h16 << 16);
}

// ---- input projection via MFMA: x[m][n] = emb[tok(m)] . w_ih[n] + bias[n] ----
__global__ __launch_bounds__(256) void inproj_mfma(const int* __restrict__ inp,
    const float* __restrict__ emb, const uint16_t* __restrict__ wih16,
    const float* __restrict__ bias, __hip_bfloat16* __restrict__ xf,
    __hip_bfloat16* __restrict__ xb){
  __shared__ uint16_t As[64][72];    // A[m][k] bf16, +8 pad
  __shared__ uint16_t Bs[128][72];   // B^T[c][k] = w_ih[n0+c][k] bf16, +8 pad
  __shared__ int toks[64];
  int bm = blockIdx.x, bn = blockIdx.y;
  int tid = threadIdx.x;
  if (tid < 64) {
    int m = bm*64 + tid;                       // b = m&63, t = m>>6
    toks[tid] = inp[(m & 63)*S_LEN + (m >> 6)];
  }
  __syncthreads();
  int w = tid >> 6, l = tid & 63;
  int lr = l & 15, lg = l >> 4;
  f32x4 acc[8];
#pragma unroll
  for (int cf = 0; cf < 8; ++cf) acc[cf] = (f32x4){0.f,0.f,0.f,0.f};

  int am = tid >> 2, aq = tid & 3;             // A staging: row am, 16 k each
  int bc = tid >> 1, bh = tid & 1;             // B staging: row bc, 32 k each

  for (int k0 = 0; k0 < 256; k0 += 64) {
    {
      const float* asrc = emb + (size_t)toks[am]*256 + k0 + aq*16;
      float4 v0 = *(const float4*)(asrc+0);
      float4 v1 = *(const float4*)(asrc+4);
      float4 v2 = *(const float4*)(asrc+8);
      float4 v3 = *(const float4*)(asrc+12);
      uint16_t t16[16];
      t16[0]=f2b(v0.x); t16[1]=f2b(v0.y); t16[2]=f2b(v0.z); t16[3]=f2b(v0.w);
      t16[4]=f2b(v1.x); t16[5]=f2b(v1.y); t16[6]=f2b(v1.z); t16[7]=f2b(v1.w);
      t16[8]=f2b(v2.x); t16[9]=f2b(v2.y); t16[10]=f2b(v2.z); t16[11]=f2b(v2.w);
      t16[12]=f2b(v3.x); t16[13]=f2b(v3.y); t16[14]=f2b(v3.z); t16[15]=f2b(v3.w);
      *(uint4*)&As[am][aq*16]     = *(uint4*)&t16[0];
      *(uint4*)&As[am][aq*16 + 8] = *(uint4*)&t16[8];
    }
    {
      const uint16_t* bsrc = wih16 + (size_t)(bn*128 + bc)*256 + k0 + bh*32;
      uint4 b0 = *(const uint4*)(bsrc+0);
      uint4 b1 = *(const uint4*)(bsrc+8);
      uint4 b2 = *(const uint4*)(bsrc+16);
      uint4 b3 = *(const uint4*)(bsrc+24);
      *(uint4*)&Bs[bc][bh*32+0]  = b0;
      *(uint4*)&Bs[bc][bh*32+8]  = b1;
      *(uint4*)&Bs[bc][bh*32+16] = b2;
      *(uint4*)&Bs[bc][bh*32+24] = b3;
    }
    __syncthreads();
#pragma unroll
    for (int ks = 0; ks < 2; ++ks) {
      int koff = ks*32 + lg*8;
      bf16x8 a = *(const bf16x8*)&As[16*w + lr][koff];
#pragma unroll
      for (int cf = 0; cf < 8; ++cf) {
        bf16x8 b = *(const bf16x8*)&Bs[cf*16 + lr][koff];
        acc[cf] = __builtin_amdgcn_mfma_f32_16x16x32_bf16(a, b, acc[cf], 0, 0, 0);
      }
    }
    __syncthreads();
  }
  int n0 = bn*128;
  bool back = (n0 >= 1024);
  __hip_bfloat16* dst = back ? xb : xf;
  int nb0 = back ? (n0 - 1024) : n0;
#pragma unroll
  for (int cf = 0; cf < 8; ++cf) {
    int nc = cf*16 + lr;
    float bv = bias[n0 + nc];
#pragma unroll
    for (int r = 0; r < 4; ++r) {
      int m = bm*64 + 16*w + lg*4 + r;
      dst[(size_t)m*1024 + nb0 + nc] = __float2bfloat16(acc[cf][r] + bv);
    }
  }
}

// ---- recurrence: one wg per (dir, batch); 1024 threads; thread gc owns gate column gc ----
// Weight-stationary: 96 f16-pairs in VGPRs + 32 pairs (16 uint2 rows) in LDS per column.
// __launch_bounds__(1024, 4): 4 min-waves/EU -> VGPR cap 128 (the channel the
// backend honors; the separate amdgpu_waves_per_eu attribute was ignored in R3).
__global__ __launch_bounds__(1024, 4)
void lstm2(const uint32_t* __restrict__ wph,
    const __hip_bfloat16* __restrict__ xf, const __hip_bfloat16* __restrict__ xb,
    __hip_bfloat16* __restrict__ hout){
  int dir = blockIdx.x >> 6;
  int b = blockIdx.x & 63;
  int gc = threadIdx.x;                 // gate column 0..1023 (gate = gc>>8, unit = gc&255)
  __shared__ uint2 wl2[NLDS2][1024];    // 128 KB: pairs 96..127, two pairs per element
  __shared__ float zs[1024];            // 4 KB
  __shared__ __align__(16) _Float16 hs[256];

  const uint32_t* wp = wph + (size_t)dir*131072 + gc;
  uint32_t wreg[NREG];
#pragma unroll
  for (int r = 0; r < NREG; ++r) wreg[r] = wp[r*1024];
#pragma unroll
  for (int p = 0; p < NLDS2; ++p) {
    uint2 v;
    v.x = wp[(NREG + 2*p)*1024];
    v.y = wp[(NREG + 2*p + 1)*1024];
    wl2[p][gc] = v;
  }
  // Pin weights in VGPRs: forbid remat/sink of the loads into the loop.
#pragma unroll
  for (int r = 0; r < NREG; ++r) asm volatile("" : "+v"(wreg[r]));
  asm volatile("" ::: "memory");
  if (gc < 256) hs[gc] = (_Float16)0.f;
  float c = 0.f;
  const __hip_bfloat16* xp = (dir ? xb : xf) + (size_t)b*1024 + gc;
  __syncthreads();

  int ts0 = dir ? (S_LEN-1) : 0;
  float xv = __bfloat162float(xp[(size_t)ts0*65536]);
  for (int t = 0; t < S_LEN; ++t) {
    int ts = dir ? (S_LEN-1-t) : t;
    float xnext = xv;
    if (t + 1 < S_LEN) {
      int tn = dir ? (S_LEN-2-t) : (t+1);
      xnext = __bfloat162float(xp[(size_t)tn*65536]);
    }
    float acc0 = 0.f, acc1 = 0.f;
    const uint4* hp4 = (const uint4*)hs;   // 32 uint4 = 128 h-pairs (uniform broadcast)
#pragma unroll
    for (int q = 0; q < 24; ++q) {         // pairs 0..95 from registers
      uint4 hq = hp4[q];
      acc0 = dot2p(wreg[4*q+0], hq.x, acc0);
      acc1 = dot2p(wreg[4*q+1], hq.y, acc1);
      acc0 = dot2p(wreg[4*q+2], hq.z, acc0);
      acc1 = dot2p(wreg[4*q+3], hq.w, acc1);
    }
#pragma unroll
    for (int q = 24; q < 32; ++q) {        // pairs 96..127 from LDS (b64 reads)
      uint4 hq = hp4[q];
      uint2 wA = wl2[2*q-48][gc];
      uint2 wB = wl2[2*q-47][gc];
      acc0 = dot2p(wA.x, hq.x, acc0);
      acc1 = dot2p(wA.y, hq.y, acc1);
      acc0 = dot2p(wB.x, hq.z, acc0);
      acc1 = dot2p(wB.y, hq.w, acc1);
    }
    zs[gc] = xv + acc0 + acc1;
    __syncthreads();
    if (gc < 256) {
      float zi = zs[gc], zf = zs[gc+256], zg = zs[gc+512], zo = zs[gc+768];
      float ig = sigf(zi), fg = sigf(zf), gg = tanh_(zg), og = sigf(zo);
      c = fg*c + ig*gg;
      float hj = og * tanh_(c);
      hs[gc] = (_Float16)hj;
      hout[((size_t)ts*BATCH + b)*512 + dir*256 + gc] = __float2bfloat16(hj);
    }
    xv = xnext;
    __syncthreads();
  }
}

// ---- output projection: emissions[t*64+b][j] = h . w_out[j+1] + b_out[j+1] ----
__global__ __launch_bounds__(256) void outproj(const __hip_bfloat16* __restrict__ hb,
    const float* __restrict__ w_out, const float* __restrict__ b_out,
    float* __restrict__ em){
  __shared__ float wsm[NT*512];
  __shared__ float bsm[NT];
  int tid = threadIdx.x;
  for (int i = tid; i < NT*512; i += 256) wsm[i] = w_out[512 + i];  // rows 1..9
  if (tid < NT) bsm[tid] = b_out[1 + tid];
  __syncthreads();
  int wave = tid >> 6, l = tid & 63;
  int m = blockIdx.x*4 + wave;
  const __hip_bfloat16* hp = hb + (size_t)m*512;
  float hv[8];
#pragma unroll
  for (int q = 0; q < 8; ++q) hv[q] = __bfloat162float(hp[l + 64*q]);
  for (int jj = 0; jj < NT; ++jj) {
    float p = 0.f;
#pragma unroll
    for (int q = 0; q < 8; ++q) p += hv[q]*wsm[jj*512 + 64*q + l];
    p = wredsum(p);
    if (l == 0) em[(size_t)m*NT + jj] = p + bsm[jj];
  }
}

// ---- CRF: one wave per batch item; lanes 0..8 hold the 9-state score ----
__global__ __launch_bounds__(64) void crf(const int* __restrict__ tags,
    const float* __restrict__ em, const float* __restrict__ start_t,
    const float* __restrict__ end_t, const float* __restrict__ trans,
    float* __restrict__ part){
  int b = blockIdx.x;
  int l = threadIdx.x;
  float np = 0.f;
  for (int t = l; t < S_LEN; t += 64) {
    int tg = tags[b*S_LEN + t] - 1;
    float e = em[(size_t)(t*BATCH + b)*NT + tg];
    float tr = (t == 0) ? start_t[tg] : trans[(tags[b*S_LEN + t - 1] - 1)*NT + tg];
    np += e + tr;
  }
  float num = wredsum(np);
  num += end_t[tags[b*S_LEN + S_LEN-1] - 1];
  int j = (l < NT) ? l : 0;
  float tj[NT];
#pragma unroll
  for (int i = 0; i < NT; ++i) tj[i] = trans[i*NT + j];
  float sc = start_t[j] + em[(size_t)b*NT + j];
  for (int t = 1; t < S_LEN; ++t) {
    float e = em[(size_t)(t*BATCH + b)*NT + j];
    float m = -1e30f;
    float vals[NT];
#pragma unroll
    for (int i = 0; i < NT; ++i) { float si = __shfl(sc, i); vals[i] = si + tj[i]; m = fmaxf(m, vals[i]); }
    float ssum = 0.f;
#pragma unroll
    for (int i = 0; i < NT; ++i) ssum += __expf(vals[i] - m);
    sc = e + m + __logf(ssum);
  }
  float vj = (l < NT) ? (sc + end_t[l]) : -1e30f;
  float mx = vj;
#pragma unroll
  for (int s2 = 32; s2 > 0; s2 >>= 1) mx = fmaxf(mx, __shfl_xor(mx, s2));
  float es = __expf(vj - mx);
  es = wredsum(es);
  if (l == 0) part[b] = num - (mx + __logf(es));
}

__global__ void finalize(const float* __restrict__ part, float* __restrict__ out){
  float v = part[threadIdx.x];
  v = wredsum(v);
  if (threadIdx.x == 0) out[0] = -(v / 64.f);
}

extern "C" void kernel_launch(void* const* d_in, const int* in_sizes, int n_in,
                              void* d_out, int out_size, void* d_ws, size_t ws_size,
                              hipStream_t stream) {
  (void)in_sizes; (void)n_in; (void)out_size; (void)ws_size;
  const int*   inputs  = (const int*)d_in[0];
  const int*   tags    = (const int*)d_in[1];
  const float* emb     = (const float*)d_in[3];
  const float* w_ih_f  = (const float*)d_in[4];
  const float* w_hh_f  = (const float*)d_in[5];
  const float* b_ih_f  = (const float*)d_in[6];
  const float* b_hh_f  = (const float*)d_in[7];
  const float* w_ih_b  = (const float*)d_in[8];
  const float* w_hh_b  = (const float*)d_in[9];
  const float* b_ih_b  = (const float*)d_in[10];
  const float* b_hh_b  = (const float*)d_in[11];
  const float* w_out   = (const float*)d_in[12];
  const float* b_out   = (const float*)d_in[13];
  const float* start_t = (const float*)d_in[14];
  const float* end_t   = (const float*)d_in[15];
  const float* trans   = (const float*)d_in[16];

  char* ws = (char*)d_ws;
  size_t off = 0;
  auto alloc = [&](size_t bytes) -> void* {
    void* p = ws + off;
    off = (off + bytes + 255) & ~(size_t)255;
    return p;
  };
  __hip_bfloat16* xf  = (__hip_bfloat16*)alloc((size_t)NTOK*1024*2);
  __hip_bfloat16* xb  = (__hip_bfloat16*)alloc((size_t)NTOK*1024*2);
  __hip_bfloat16* hbf = (__hip_bfloat16*)alloc((size_t)NTOK*512*2);
  float*    em    = (float*)alloc((size_t)NTOK*NT*4);
  uint16_t* wih16 = (uint16_t*)alloc((size_t)2048*256*2);
  float*    bias  = (float*)alloc((size_t)2048*4);
  uint32_t* wph   = (uint32_t*)alloc((size_t)2*128*1024*4);
  float*    part  = (float*)alloc((size_t)64*4);

  prep2<<<2048, 256, 0, stream>>>(w_ih_f, w_ih_b, b_ih_f, b_hh_f, b_ih_b, b_hh_b, wih16, bias);
  prep_wph<<<1024, 256, 0, stream>>>(w_hh_f, w_hh_b, wph);
  inproj_mfma<<<dim3(256, 16), 256, 0, stream>>>(inputs, emb, wih16, bias, xf, xb);
  lstm2<<<128, 1024, 0, stream>>>(wph, xf, xb, hbf);
  outproj<<<4096, 256, 0, stream>>>(hbf, w_out, b_out, em);
  crf<<<64, 64, 0, stream>>>(tags, em, start_t, end_t, trans, part);
  finalize<<<1, 64, 0, stream>>>(part, (float*)d_out);
}